// Round 1
// baseline (75695.142 us; speedup 1.0000x reference)
//
#include <hip/hip_runtime.h>
#include <cstdint>

#define NB 128   // batch
#define NS 1024  // seq len
#define NV 128   // vocab/input dim
#define NH 256   // hidden
#define NG 1024  // 4*NH

typedef _Float16 f16;
typedef _Float16 h2 __attribute__((ext_vector_type(2)));

static __device__ __forceinline__ float fdot2(uint32_t a, uint32_t b, float c) {
  h2 av = __builtin_bit_cast(h2, a);
  h2 bv = __builtin_bit_cast(h2, b);
  return __builtin_amdgcn_fdot2(av, bv, c, false);
}
static __device__ __forceinline__ uint32_t pkh(float a, float b) {
  union { h2 h; uint32_t u; } cv;
  cv.h = h2{(f16)a, (f16)b};
  return cv.u;
}
static __device__ __forceinline__ float sigm(float x) {
  return 1.0f / (1.0f + __expf(-x));
}
static __device__ __forceinline__ float tanh_(float x) {
  // 1 - 2/(exp(2x)+1): exact at extremes (inf -> 1, 0 -> -1), no NaN
  return 1.0f - 2.0f / (__expf(2.0f * x) + 1.0f);
}

// ---------------------------------------------------------------------------
// Layer-0 scan. One WG per batch element, 1024 threads = 16 waves.
// Thread t: cg = t&3 (column group), rb = t>>2 (hidden unit 0..255).
// Owns gate rows {rb, rb+256, rb+512, rb+768}:
//   W_ih slice: 32 cols starting at 32*cg  (V=128)
//   W_hh slice: 64 cols starting at 64*cg  (H=256)
// Weights register-resident as packed f16 pairs. Quad shfl_xor reduce.
// ---------------------------------------------------------------------------
__global__ __launch_bounds__(1024) void scan0_kernel(
    const float* __restrict__ x, const float* __restrict__ Wih,
    const float* __restrict__ Whh, const float* __restrict__ bih,
    const float* __restrict__ bhh, f16* __restrict__ h0g) {
  const int b = blockIdx.x;
  const int tid = threadIdx.x;
  const int cg = tid & 3;
  const int rb = tid >> 2;

  __shared__ uint32_t xbuf[2][64];   // x_t as 64 f16-pairs (128 f32 values)
  __shared__ uint32_t hbuf[2][128];  // h as 128 f16-pairs (256 values)

  uint32_t wih[4][16];
  uint32_t whh[4][32];
  float bias[4];
#pragma unroll
  for (int g = 0; g < 4; ++g) {
    const int row = rb + 256 * g;
    const float* wr = Wih + (size_t)row * NV + 32 * cg;
#pragma unroll
    for (int k = 0; k < 8; ++k) {
      float4 w4 = *(const float4*)(wr + 4 * k);
      wih[g][2 * k]     = pkh(w4.x, w4.y);
      wih[g][2 * k + 1] = pkh(w4.z, w4.w);
    }
    const float* wr2 = Whh + (size_t)row * NH + 64 * cg;
#pragma unroll
    for (int k = 0; k < 16; ++k) {
      float4 w4 = *(const float4*)(wr2 + 4 * k);
      whh[g][2 * k]     = pkh(w4.x, w4.y);
      whh[g][2 * k + 1] = pkh(w4.z, w4.w);
    }
    bias[g] = bih[row] + bhh[row];
  }

  if (tid < 128) { hbuf[0][tid] = 0u; hbuf[1][tid] = 0u; }
  if (tid < 64) {
    const float2 x2 = *(const float2*)(x + ((size_t)b * NS + 0) * NV + 2 * tid);
    xbuf[0][tid] = pkh(x2.x, x2.y);
  }
  float c = 0.0f;
  __syncthreads();

#pragma unroll 1
  for (int t = 0; t < NS; ++t) {
    const int cur = t & 1, nxt = cur ^ 1;

    // issue next-step x loads early (latency hidden under the dots)
    float2 x2 = {0.f, 0.f};
    if (tid < 64 && t + 1 < NS)
      x2 = *(const float2*)(x + ((size_t)b * NS + (t + 1)) * NV + 2 * tid);

    float acc[4];
#pragma unroll
    for (int g = 0; g < 4; ++g) acc[g] = (cg == 0) ? bias[g] : 0.0f;

    // phase A: x_t contribution (W_ih slice)
#pragma unroll
    for (int q = 0; q < 4; ++q) {
      uint4 xv = *(const uint4*)&xbuf[cur][16 * cg + 4 * q];
      uint32_t xw[4] = {xv.x, xv.y, xv.z, xv.w};
#pragma unroll
      for (int j = 0; j < 4; ++j) {
#pragma unroll
        for (int g = 0; g < 4; ++g)
          acc[g] = fdot2(wih[g][4 * q + j], xw[j], acc[g]);
      }
    }
    // phase B: recurrence (W_hh slice, h from previous step)
#pragma unroll
    for (int q = 0; q < 8; ++q) {
      uint4 hv = *(const uint4*)&hbuf[cur][32 * cg + 4 * q];
      uint32_t hw[4] = {hv.x, hv.y, hv.z, hv.w};
#pragma unroll
      for (int j = 0; j < 4; ++j) {
#pragma unroll
        for (int g = 0; g < 4; ++g)
          acc[g] = fdot2(whh[g][4 * q + j], hw[j], acc[g]);
      }
    }
    // quad reduce: lanes 4*rb..4*rb+3 hold the 4 column-partials of unit rb
#pragma unroll
    for (int g = 0; g < 4; ++g) {
      acc[g] += __shfl_xor(acc[g], 1);
      acc[g] += __shfl_xor(acc[g], 2);
    }
    // gates (PyTorch order i, f, g, o); redundant in all 4 quad lanes
    const float gi = sigm(acc[0]);
    const float gf = sigm(acc[1]);
    const float gc = tanh_(acc[2]);
    const float go = sigm(acc[3]);
    c = gf * c + gi * gc;
    const float hn = go * tanh_(c);
    if (cg == 0) {
      ((f16*)hbuf[nxt])[rb] = (f16)hn;
      h0g[((size_t)b * NS + t) * NH + rb] = (f16)hn;
    }
    if (tid < 64 && t + 1 < NS) xbuf[nxt][tid] = pkh(x2.x, x2.y);
    __syncthreads();
  }
}

// ---------------------------------------------------------------------------
// Layer-1 scan + fused output projection.
// Same decomposition for W_ih1/W_hh1 (both 64-col slices, H=256 input).
// Output projection: thread t = (vr = t>>3, cg8 = t&7) owns W_out row vr,
// 32 cols at 32*cg8; computed for step t-1 (after h1(t-1) is published).
// ---------------------------------------------------------------------------
__global__ __launch_bounds__(1024) void scan1_kernel(
    const f16* __restrict__ h0g, const float* __restrict__ Wih,
    const float* __restrict__ Whh, const float* __restrict__ bih,
    const float* __restrict__ bhh, const float* __restrict__ Wout,
    const float* __restrict__ bout, float* __restrict__ out) {
  const int b = blockIdx.x;
  const int tid = threadIdx.x;
  const int cg = tid & 3;
  const int rb = tid >> 2;
  const int cg8 = tid & 7;
  const int vr = tid >> 3;

  __shared__ uint32_t ibuf[2][128];  // layer-0 h (input to layer 1)
  __shared__ uint32_t hbuf[2][128];  // layer-1 h

  uint32_t wih[4][32];
  uint32_t whh[4][32];
  uint32_t wo[16];
  float bias[4];
#pragma unroll
  for (int g = 0; g < 4; ++g) {
    const int row = rb + 256 * g;
    const float* wr = Wih + (size_t)row * NH + 64 * cg;
#pragma unroll
    for (int k = 0; k < 16; ++k) {
      float4 w4 = *(const float4*)(wr + 4 * k);
      wih[g][2 * k]     = pkh(w4.x, w4.y);
      wih[g][2 * k + 1] = pkh(w4.z, w4.w);
    }
    const float* wr2 = Whh + (size_t)row * NH + 64 * cg;
#pragma unroll
    for (int k = 0; k < 16; ++k) {
      float4 w4 = *(const float4*)(wr2 + 4 * k);
      whh[g][2 * k]     = pkh(w4.x, w4.y);
      whh[g][2 * k + 1] = pkh(w4.z, w4.w);
    }
    bias[g] = bih[row] + bhh[row];
  }
#pragma unroll
  for (int k = 0; k < 8; ++k) {
    float4 w4 = *(const float4*)(Wout + (size_t)vr * NH + 32 * cg8 + 4 * k);
    wo[2 * k]     = pkh(w4.x, w4.y);
    wo[2 * k + 1] = pkh(w4.z, w4.w);
  }
  const float bo = bout[vr];

  if (tid < 128) {
    hbuf[0][tid] = 0u;
    hbuf[1][tid] = 0u;
    ibuf[0][tid] = ((const uint32_t*)h0g)[((size_t)b * NS + 0) * (NH / 2) + tid];
  }
  float c = 0.0f;
  __syncthreads();

#pragma unroll 1
  for (int t = 0; t <= NS; ++t) {
    const int cur = t & 1, nxt = cur ^ 1;

    // output projection for step t-1 (h1(t-1) was published into hbuf[cur])
    if (t > 0) {
      float oa = 0.0f;
#pragma unroll
      for (int q = 0; q < 4; ++q) {
        uint4 hv = *(const uint4*)&hbuf[cur][16 * cg8 + 4 * q];
        uint32_t hw[4] = {hv.x, hv.y, hv.z, hv.w};
#pragma unroll
        for (int j = 0; j < 4; ++j) oa = fdot2(wo[4 * q + j], hw[j], oa);
      }
      oa += __shfl_xor(oa, 1);
      oa += __shfl_xor(oa, 2);
      oa += __shfl_xor(oa, 4);
      if (cg8 == 0) out[((size_t)b * NS + (t - 1)) * NV + vr] = oa + bo;
    }
    if (t == NS) break;

    // issue next-step layer-0 h loads early
    uint32_t inx = 0u;
    if (tid < 128 && t + 1 < NS)
      inx = ((const uint32_t*)h0g)[((size_t)b * NS + (t + 1)) * (NH / 2) + tid];

    float acc[4];
#pragma unroll
    for (int g = 0; g < 4; ++g) acc[g] = (cg == 0) ? bias[g] : 0.0f;

    // phase A: input contribution (W_ih1 . h0_t)
#pragma unroll
    for (int q = 0; q < 8; ++q) {
      uint4 xv = *(const uint4*)&ibuf[cur][32 * cg + 4 * q];
      uint32_t xw[4] = {xv.x, xv.y, xv.z, xv.w};
#pragma unroll
      for (int j = 0; j < 4; ++j) {
#pragma unroll
        for (int g = 0; g < 4; ++g)
          acc[g] = fdot2(wih[g][4 * q + j], xw[j], acc[g]);
      }
    }
    // phase B: recurrence (W_hh1 . h1_{t-1})
#pragma unroll
    for (int q = 0; q < 8; ++q) {
      uint4 hv = *(const uint4*)&hbuf[cur][32 * cg + 4 * q];
      uint32_t hw[4] = {hv.x, hv.y, hv.z, hv.w};
#pragma unroll
      for (int j = 0; j < 4; ++j) {
#pragma unroll
        for (int g = 0; g < 4; ++g)
          acc[g] = fdot2(whh[g][4 * q + j], hw[j], acc[g]);
      }
    }
#pragma unroll
    for (int g = 0; g < 4; ++g) {
      acc[g] += __shfl_xor(acc[g], 1);
      acc[g] += __shfl_xor(acc[g], 2);
    }
    const float gi = sigm(acc[0]);
    const float gf = sigm(acc[1]);
    const float gc = tanh_(acc[2]);
    const float go = sigm(acc[3]);
    c = gf * c + gi * gc;
    const float hn = go * tanh_(c);
    if (cg == 0) ((f16*)hbuf[nxt])[rb] = (f16)hn;
    if (tid < 128 && t + 1 < NS) ibuf[nxt][tid] = inx;
    __syncthreads();
  }
}

extern "C" void kernel_launch(void* const* d_in, const int* in_sizes, int n_in,
                              void* d_out, int out_size, void* d_ws, size_t ws_size,
                              hipStream_t stream) {
  const float* x    = (const float*)d_in[0];
  const float* Wih0 = (const float*)d_in[1];
  const float* Whh0 = (const float*)d_in[2];
  const float* bih0 = (const float*)d_in[3];
  const float* bhh0 = (const float*)d_in[4];
  const float* Wih1 = (const float*)d_in[5];
  const float* Whh1 = (const float*)d_in[6];
  const float* bih1 = (const float*)d_in[7];
  const float* bhh1 = (const float*)d_in[8];
  const float* Wout = (const float*)d_in[9];
  const float* bout = (const float*)d_in[10];

  f16* h0g = (f16*)d_ws;  // B*S*H f16 = 64 MB scratch
  float* out = (float*)d_out;

  scan0_kernel<<<NB, 1024, 0, stream>>>(x, Wih0, Whh0, bih0, bhh0, h0g);
  scan1_kernel<<<NB, 1024, 0, stream>>>(h0g, Wih1, Whh1, bih1, bhh1, Wout, bout, out);
}

// Round 2
// 16291.454 us; speedup vs baseline: 4.6463x; 4.6463x over previous
//
#include <hip/hip_runtime.h>
#include <cstdint>

#define NB 128   // batch
#define NS 1024  // seq len
#define NV 128   // input dim
#define NH 256   // hidden

typedef _Float16 f16;
typedef _Float16 h2 __attribute__((ext_vector_type(2)));
typedef uint32_t u32;

#define SENT 0xFFFFFFFFu  // 2x f16 NaN — impossible for sigmoid*tanh outputs

static __device__ __forceinline__ float fdot2(u32 a, u32 b, float c) {
  return __builtin_amdgcn_fdot2(__builtin_bit_cast(h2, a),
                                __builtin_bit_cast(h2, b), c, false);
}
static __device__ __forceinline__ u32 pkh(float a, float b) {
  union { h2 h; u32 u; } cv; cv.h = h2{(f16)a, (f16)b}; return cv.u;
}
static __device__ __forceinline__ float sigm(float x) { return 1.0f / (1.0f + __expf(-x)); }
static __device__ __forceinline__ float tanh_(float x) { return 1.0f - 2.0f / (__expf(2.0f * x) + 1.0f); }

static __device__ __forceinline__ u32 gload(const u32* p) {
  return __hip_atomic_load(p, __ATOMIC_RELAXED, __HIP_MEMORY_SCOPE_AGENT);
}
static __device__ __forceinline__ void gstore(u32* p, u32 v) {
  __hip_atomic_store(p, v, __ATOMIC_RELAXED, __HIP_MEMORY_SCOPE_AGENT);
}

// ---------------------------------------------------------------------------
// scan0: layer-0 LSTM. 256 WGs = (batch b, half) — WG owns 512 gate rows
// (units [half*128, half*128+128), gates i/f/g/o). 1024 threads:
// rb2 = tid>>3 (unit within half), cg = tid&7 (column-eighth).
// Per-thread register weights: Wih0 4x16 cols (32 u32), Whh0 4x(16 own +16
// partner) cols (64 u32). Partner h exchanged via h0g slots w/ 0xFF sentinel.
// h0g slot layout: [b][t][128 u32] = full h (f16 pairs), halves contiguous.
// ---------------------------------------------------------------------------
__global__ __launch_bounds__(1024) void scan0_kernel(
    const float* __restrict__ x, const float* __restrict__ Wih,
    const float* __restrict__ Whh, const float* __restrict__ bih,
    const float* __restrict__ bhh, u32* __restrict__ h0g) {
  const int blk = blockIdx.x;
  const int b = (blk & 7) | ((blk >> 4) << 3);  // pair (blk, blk^8) same XCD
  const int half = (blk >> 3) & 1;
  const int oh = 1 - half;
  const int tid = threadIdx.x;
  const int cg = tid & 7;
  const int rb2 = tid >> 3;

  __shared__ u32 xbuf[64];     // x_t as 64 f16 pairs
  __shared__ u32 hbuf[128];    // full h(t-1): [half][64 u32]
  __shared__ float biasL[512];

  u32 wih_[4][8], who_[4][8], whp_[4][8];
#pragma unroll
  for (int g = 0; g < 4; ++g) {
    const int row = g * 256 + half * 128 + rb2;
    const float* pw = Wih + (size_t)row * NV + cg * 16;
#pragma unroll
    for (int k = 0; k < 4; ++k) {
      float4 w4 = *(const float4*)(pw + 4 * k);
      wih_[g][2 * k] = pkh(w4.x, w4.y); wih_[g][2 * k + 1] = pkh(w4.z, w4.w);
    }
    const float* po = Whh + (size_t)row * NH + half * 128 + cg * 16;
#pragma unroll
    for (int k = 0; k < 4; ++k) {
      float4 w4 = *(const float4*)(po + 4 * k);
      who_[g][2 * k] = pkh(w4.x, w4.y); who_[g][2 * k + 1] = pkh(w4.z, w4.w);
    }
    const float* pp = Whh + (size_t)row * NH + oh * 128 + cg * 16;
#pragma unroll
    for (int k = 0; k < 4; ++k) {
      float4 w4 = *(const float4*)(pp + 4 * k);
      whp_[g][2 * k] = pkh(w4.x, w4.y); whp_[g][2 * k + 1] = pkh(w4.z, w4.w);
    }
  }
  if (tid < 512) {
    const int g = tid >> 7, r = tid & 127;
    const int row = g * 256 + half * 128 + r;
    biasL[tid] = bih[row] + bhh[row];
  }
  if (tid < 128) hbuf[tid] = 0u;
  if (tid < 64) {
    float2 x2 = *(const float2*)(x + (size_t)b * NS * NV + 2 * tid);
    xbuf[tid] = pkh(x2.x, x2.y);
  }
  __syncthreads();

  float c = 0.0f;
#pragma unroll 1
  for (int t = 0; t < NS; ++t) {
    // wave1: prefetch x(t+1)
    float2 x2;
    if (tid >= 64 && tid < 128) {
      const int tn = (t + 1 < NS) ? t + 1 : t;
      x2 = *(const float2*)(x + ((size_t)b * NS + tn) * NV + 2 * (tid - 64));
    }
    // wave0: issue partner-h poll load (checked after phase A)
    u32 pv = 0;
    const u32* pslot = h0g + ((size_t)b * NS + (t > 0 ? t - 1 : 0)) * 128 + oh * 64;
    if (tid < 64 && t > 0) pv = gload(pslot + tid);

    float acc[4] = {0.f, 0.f, 0.f, 0.f};
    // phase A: Wih·x_t + Whh_own·h_own(t-1)
#pragma unroll
    for (int q = 0; q < 2; ++q) {
      uint4 xq = *(const uint4*)&xbuf[cg * 8 + 4 * q];
      u32 xw[4] = {xq.x, xq.y, xq.z, xq.w};
#pragma unroll
      for (int j = 0; j < 4; ++j)
#pragma unroll
        for (int g = 0; g < 4; ++g) acc[g] = fdot2(wih_[g][4 * q + j], xw[j], acc[g]);
    }
#pragma unroll
    for (int q = 0; q < 2; ++q) {
      uint4 hq = *(const uint4*)&hbuf[half * 64 + cg * 8 + 4 * q];
      u32 hw[4] = {hq.x, hq.y, hq.z, hq.w};
#pragma unroll
      for (int j = 0; j < 4; ++j)
#pragma unroll
        for (int g = 0; g < 4; ++g) acc[g] = fdot2(who_[g][4 * q + j], hw[j], acc[g]);
    }
    // wave0: complete poll, stage partner half
    if (tid < 64 && t > 0) {
      while (pv == SENT) { __builtin_amdgcn_s_sleep(8); pv = gload(pslot + tid); }
      hbuf[oh * 64 + tid] = pv;
    }
    __syncthreads();  // B1
    // phase B: Whh_partner·h_partner(t-1)
#pragma unroll
    for (int q = 0; q < 2; ++q) {
      uint4 hq = *(const uint4*)&hbuf[oh * 64 + cg * 8 + 4 * q];
      u32 hw[4] = {hq.x, hq.y, hq.z, hq.w};
#pragma unroll
      for (int j = 0; j < 4; ++j)
#pragma unroll
        for (int g = 0; g < 4; ++g) acc[g] = fdot2(whp_[g][4 * q + j], hw[j], acc[g]);
    }
#pragma unroll
    for (int g = 0; g < 4; ++g) {
      acc[g] += __shfl_xor(acc[g], 1);
      acc[g] += __shfl_xor(acc[g], 2);
      acc[g] += __shfl_xor(acc[g], 4);
    }
    if (cg == 0) {
      const float gi = sigm(acc[0] + biasL[rb2]);
      const float gf = sigm(acc[1] + biasL[128 + rb2]);
      const float gg = tanh_(acc[2] + biasL[256 + rb2]);
      const float go = sigm(acc[3] + biasL[384 + rb2]);
      c = gf * c + gi * gg;
      ((f16*)hbuf)[half * 128 + rb2] = (f16)(go * tanh_(c));
    }
    if (tid >= 64 && tid < 128 && t + 1 < NS) xbuf[tid - 64] = pkh(x2.x, x2.y);
    __syncthreads();  // B2
    // wave1: publish own h(t) half (atomic u32 stores -> agent-visible)
    if (tid >= 64 && tid < 128)
      gstore(h0g + ((size_t)b * NS + t) * 128 + half * 64 + (tid - 64),
             hbuf[half * 64 + (tid - 64)]);
  }
}

// ---------------------------------------------------------------------------
// scan1: layer-1 LSTM. Same decomposition. Per-thread: Whh1 4x(16+16) cols in
// regs (64 u32); Wih1 4x32 cols = 64 u32 split 32 reg + 32 LDS (128 KiB,
// k-major conflict-free). h1 published into d_out slots (sentinel-polled by
// partner); h0 input read from h0g (scan0 complete, plain loads).
// ---------------------------------------------------------------------------
__global__ __launch_bounds__(1024) void scan1_kernel(
    const u32* __restrict__ h0g, const float* __restrict__ Wih,
    const float* __restrict__ Whh, const float* __restrict__ bih,
    const float* __restrict__ bhh, u32* __restrict__ outw) {
  const int blk = blockIdx.x;
  const int b = (blk & 7) | ((blk >> 4) << 3);
  const int half = (blk >> 3) & 1;
  const int oh = 1 - half;
  const int tid = threadIdx.x;
  const int cg = tid & 7;
  const int rb2 = tid >> 3;

  __shared__ u32 wihL[8][1024][4];  // 128 KiB: quads 2,3 of each gate's Wih1 slice
  __shared__ u32 i0buf[128];        // h0(t) full (f16 pairs)
  __shared__ u32 hbuf[128];         // h1(t-1) full
  __shared__ float biasL[512];

  u32 wihR[4][8], who_[4][8], whp_[4][8];
#pragma unroll
  for (int g = 0; g < 4; ++g) {
    const int row = g * 256 + half * 128 + rb2;
    const float* pw = Wih + (size_t)row * NH + cg * 32;
    u32 wtmp[16];
#pragma unroll
    for (int k = 0; k < 8; ++k) {
      float4 w4 = *(const float4*)(pw + 4 * k);
      wtmp[2 * k] = pkh(w4.x, w4.y); wtmp[2 * k + 1] = pkh(w4.z, w4.w);
    }
#pragma unroll
    for (int j = 0; j < 8; ++j) wihR[g][j] = wtmp[j];
#pragma unroll
    for (int j = 0; j < 4; ++j) wihL[g][tid][j] = wtmp[8 + j];
#pragma unroll
    for (int j = 0; j < 4; ++j) wihL[4 + g][tid][j] = wtmp[12 + j];
    const float* po = Whh + (size_t)row * NH + half * 128 + cg * 16;
#pragma unroll
    for (int k = 0; k < 4; ++k) {
      float4 w4 = *(const float4*)(po + 4 * k);
      who_[g][2 * k] = pkh(w4.x, w4.y); who_[g][2 * k + 1] = pkh(w4.z, w4.w);
    }
    const float* pp = Whh + (size_t)row * NH + oh * 128 + cg * 16;
#pragma unroll
    for (int k = 0; k < 4; ++k) {
      float4 w4 = *(const float4*)(pp + 4 * k);
      whp_[g][2 * k] = pkh(w4.x, w4.y); whp_[g][2 * k + 1] = pkh(w4.z, w4.w);
    }
  }
  if (tid < 512) {
    const int g = tid >> 7, r = tid & 127;
    const int row = g * 256 + half * 128 + r;
    biasL[tid] = bih[row] + bhh[row];
  }
  if (tid < 128) {
    hbuf[tid] = 0u;
    i0buf[tid] = h0g[(size_t)b * NS * 128 + tid];  // h0(0)
  }
  __syncthreads();

  float c = 0.0f;
#pragma unroll 1
  for (int t = 0; t < NS; ++t) {
    // wave1: prefetch h0(t+1)
    uint2 iv;
    if (tid >= 64 && tid < 128) {
      const int tn = (t + 1 < NS) ? t + 1 : t;
      iv = *(const uint2*)(h0g + ((size_t)b * NS + tn) * 128 + 2 * (tid - 64));
    }
    // wave0: issue partner-h1 poll
    u32 pv = 0;
    const u32* pslot = outw + ((size_t)b * NS + (t > 0 ? t - 1 : 0)) * 128 + oh * 64;
    if (tid < 64 && t > 0) pv = gload(pslot + tid);

    float acc[4] = {0.f, 0.f, 0.f, 0.f};
    // phase A: Wih1·h0(t)  (quads 0,1 from regs; 2,3 from LDS)
#pragma unroll
    for (int q = 0; q < 4; ++q) {
      uint4 iq = *(const uint4*)&i0buf[cg * 16 + 4 * q];
      u32 iw[4] = {iq.x, iq.y, iq.z, iq.w};
      if (q < 2) {
#pragma unroll
        for (int j = 0; j < 4; ++j)
#pragma unroll
          for (int g = 0; g < 4; ++g) acc[g] = fdot2(wihR[g][4 * q + j], iw[j], acc[g]);
      } else {
        uint4 wg[4];
#pragma unroll
        for (int g = 0; g < 4; ++g) wg[g] = *(const uint4*)wihL[(q - 2) * 4 + g][tid];
#pragma unroll
        for (int j = 0; j < 4; ++j)
#pragma unroll
          for (int g = 0; g < 4; ++g)
            acc[g] = fdot2(((const u32*)&wg[g])[j], iw[j], acc[g]);
      }
    }
    // + Whh1_own·h1_own(t-1)
#pragma unroll
    for (int q = 0; q < 2; ++q) {
      uint4 hq = *(const uint4*)&hbuf[half * 64 + cg * 8 + 4 * q];
      u32 hw[4] = {hq.x, hq.y, hq.z, hq.w};
#pragma unroll
      for (int j = 0; j < 4; ++j)
#pragma unroll
        for (int g = 0; g < 4; ++g) acc[g] = fdot2(who_[g][4 * q + j], hw[j], acc[g]);
    }
    if (tid < 64 && t > 0) {
      while (pv == SENT) { __builtin_amdgcn_s_sleep(8); pv = gload(pslot + tid); }
      hbuf[oh * 64 + tid] = pv;
    }
    __syncthreads();  // B1
    // phase B: Whh1_partner·h1_partner(t-1)
#pragma unroll
    for (int q = 0; q < 2; ++q) {
      uint4 hq = *(const uint4*)&hbuf[oh * 64 + cg * 8 + 4 * q];
      u32 hw[4] = {hq.x, hq.y, hq.z, hq.w};
#pragma unroll
      for (int j = 0; j < 4; ++j)
#pragma unroll
        for (int g = 0; g < 4; ++g) acc[g] = fdot2(whp_[g][4 * q + j], hw[j], acc[g]);
    }
#pragma unroll
    for (int g = 0; g < 4; ++g) {
      acc[g] += __shfl_xor(acc[g], 1);
      acc[g] += __shfl_xor(acc[g], 2);
      acc[g] += __shfl_xor(acc[g], 4);
    }
    if (cg == 0) {
      const float gi = sigm(acc[0] + biasL[rb2]);
      const float gf = sigm(acc[1] + biasL[128 + rb2]);
      const float gg = tanh_(acc[2] + biasL[256 + rb2]);
      const float go = sigm(acc[3] + biasL[384 + rb2]);
      c = gf * c + gi * gg;
      ((f16*)hbuf)[half * 128 + rb2] = (f16)(go * tanh_(c));
    }
    if (tid >= 64 && tid < 128 && t + 1 < NS) {
      i0buf[2 * (tid - 64)] = iv.x;
      i0buf[2 * (tid - 64) + 1] = iv.y;
    }
    __syncthreads();  // B2
    // wave1: publish own h1(t) half into d_out slot
    if (tid >= 64 && tid < 128)
      gstore(outw + ((size_t)b * NS + t) * 128 + half * 64 + (tid - 64),
             hbuf[half * 64 + (tid - 64)]);
  }
}

// ---------------------------------------------------------------------------
// outproj: out = Wout·h1 + b, IN PLACE over d_out (h1 f16 slot bytes == out
// f32 row bytes). Block = (b, 64-step tile); stage h1 tile to LDS, compute,
// barrier, overwrite. Thread: vq = tid>>3 (out row), p = tid&7 (col eighth,
// 32 cols in regs). 8-lane shfl reduce.
// ---------------------------------------------------------------------------
__global__ __launch_bounds__(1024) void outproj_kernel(
    const float* __restrict__ Wout, const float* __restrict__ bout,
    u32* __restrict__ io) {
  const int bs = blockIdx.x;           // 2048 blocks
  const int b = bs >> 4;
  const int t0 = (bs & 15) * 64;
  const int tid = threadIdx.x;
  const int p = tid & 7;
  const int vq = tid >> 3;

  __shared__ u32 h1L[64 * 128];
  __shared__ float outL[64 * 128];

  const u32* src = io + ((size_t)b * NS + t0) * 128;
  uint4 s0 = *(const uint4*)(src + (size_t)tid * 8);
  uint4 s1 = *(const uint4*)(src + (size_t)tid * 8 + 4);

  u32 wo[16];
  const float* pw = Wout + (size_t)vq * NH + p * 32;
#pragma unroll
  for (int k = 0; k < 8; ++k) {
    float4 w4 = *(const float4*)(pw + 4 * k);
    wo[2 * k] = pkh(w4.x, w4.y); wo[2 * k + 1] = pkh(w4.z, w4.w);
  }
  const float bo = bout[vq];

  *(uint4*)&h1L[tid * 8] = s0;
  *(uint4*)&h1L[tid * 8 + 4] = s1;
  __syncthreads();

#pragma unroll 4
  for (int s = 0; s < 64; ++s) {
    float oa = 0.0f;
#pragma unroll
    for (int q = 0; q < 4; ++q) {
      uint4 hq = *(const uint4*)&h1L[s * 128 + p * 16 + 4 * q];
      u32 hw[4] = {hq.x, hq.y, hq.z, hq.w};
#pragma unroll
      for (int j = 0; j < 4; ++j) oa = fdot2(wo[4 * q + j], hw[j], oa);
    }
    oa += __shfl_xor(oa, 1);
    oa += __shfl_xor(oa, 2);
    oa += __shfl_xor(oa, 4);
    if (p == 0) outL[s * 128 + vq] = oa + bo;
  }
  __syncthreads();

  float* df = (float*)(io + ((size_t)b * NS + t0) * 128);
  *(float4*)(df + (size_t)tid * 8) = *(float4*)&outL[tid * 8];
  *(float4*)(df + (size_t)tid * 8 + 4) = *(float4*)&outL[tid * 8 + 4];
}

extern "C" void kernel_launch(void* const* d_in, const int* in_sizes, int n_in,
                              void* d_out, int out_size, void* d_ws, size_t ws_size,
                              hipStream_t stream) {
  const float* x    = (const float*)d_in[0];
  const float* Wih0 = (const float*)d_in[1];
  const float* Whh0 = (const float*)d_in[2];
  const float* bih0 = (const float*)d_in[3];
  const float* bhh0 = (const float*)d_in[4];
  const float* Wih1 = (const float*)d_in[5];
  const float* Whh1 = (const float*)d_in[6];
  const float* bih1 = (const float*)d_in[7];
  const float* bhh1 = (const float*)d_in[8];
  const float* Wout = (const float*)d_in[9];
  const float* bout = (const float*)d_in[10];

  u32* h0g = (u32*)d_ws;   // [B][S][128 u32] = 64 MiB (known-safe ws usage)
  u32* hw1 = (u32*)d_out;  // h1 slots live inside d_out, overwritten in place

  const size_t slot_bytes = (size_t)NB * NS * 128 * 4;  // 64 MiB each
  hipMemsetAsync(d_ws, 0xFF, slot_bytes, stream);       // sentinel for scan0 exchange
  hipMemsetAsync(d_out, 0xFF, slot_bytes, stream);      // sentinel for scan1 exchange

  scan0_kernel<<<256, 1024, 0, stream>>>(x, Wih0, Whh0, bih0, bhh0, h0g);
  scan1_kernel<<<256, 1024, 0, stream>>>(h0g, Wih1, Whh1, bih1, bhh1, hw1);
  outproj_kernel<<<2048, 1024, 0, stream>>>(Wout, bout, hw1);
}

// Round 3
// 16117.448 us; speedup vs baseline: 4.6965x; 1.0108x over previous
//
#include <hip/hip_runtime.h>
#include <cstdint>

#define NB 128   // batch
#define NS 1024  // seq len
#define NV 128   // input dim
#define NH 256   // hidden

typedef _Float16 f16;
typedef _Float16 h2 __attribute__((ext_vector_type(2)));
typedef uint32_t u32;

#define SENT 0xFFFFFFFFu  // 2x f16 NaN — impossible for sigmoid*tanh outputs

static __device__ __forceinline__ float fdot2(u32 a, u32 b, float c) {
  return __builtin_amdgcn_fdot2(__builtin_bit_cast(h2, a),
                                __builtin_bit_cast(h2, b), c, false);
}
static __device__ __forceinline__ u32 pkh(float a, float b) {
  union { h2 h; u32 u; } cv; cv.h = h2{(f16)a, (f16)b}; return cv.u;
}
static __device__ __forceinline__ float sigm(float x) { return 1.0f / (1.0f + __expf(-x)); }
static __device__ __forceinline__ float tanh_(float x) { return 1.0f - 2.0f / (__expf(2.0f * x) + 1.0f); }

static __device__ __forceinline__ u32 gload(const u32* p) {
  return __hip_atomic_load(p, __ATOMIC_RELAXED, __HIP_MEMORY_SCOPE_AGENT);
}
static __device__ __forceinline__ void gstore(u32* p, u32 v) {
  __hip_atomic_store(p, v, __ATOMIC_RELAXED, __HIP_MEMORY_SCOPE_AGENT);
}

// ---------------------------------------------------------------------------
// scan0: layer-0 LSTM. 256 WGs = (batch b, half). WG owns 512 gate rows.
// rb2 = tid>>3 (unit in half), cg = tid&7 (column-eighth).
// W_ih0 slice now in LDS (8x uint4[1024], conflict-free stride-16B reads);
// Whh own/partner halves register-resident (64 u32).
// __launch_bounds__(1024,4): 4 waves/EU -> 1 WG/CU -> 128-VGPR budget.
// ---------------------------------------------------------------------------
__global__ __launch_bounds__(1024, 4) void scan0_kernel(
    const float* __restrict__ x, const float* __restrict__ Wih,
    const float* __restrict__ Whh, const float* __restrict__ bih,
    const float* __restrict__ bhh, u32* __restrict__ h0g) {
  const int blk = blockIdx.x;
  const int b = (blk & 7) | ((blk >> 4) << 3);  // pair (blk, blk^8) same XCD
  const int half = (blk >> 3) & 1;
  const int oh = 1 - half;
  const int tid = threadIdx.x;
  const int cg = tid & 7;
  const int rb2 = tid >> 3;

  __shared__ uint4 wihL[8][1024];  // 128 KiB: per-thread Wih0 slice (2 uint4/gate)
  __shared__ u32 xbuf[64];         // x_t as 64 f16 pairs
  __shared__ u32 hbuf[128];        // full h(t-1): [half][64 u32]
  __shared__ float biasL[512];

  u32 who_[4][8], whp_[4][8];
#pragma unroll
  for (int g = 0; g < 4; ++g) {
    const int row = g * 256 + half * 128 + rb2;
    const float* pw = Wih + (size_t)row * NV + cg * 16;
    {
      float4 a = *(const float4*)(pw + 0);
      float4 c = *(const float4*)(pw + 4);
      wihL[2 * g][tid] = uint4{pkh(a.x, a.y), pkh(a.z, a.w), pkh(c.x, c.y), pkh(c.z, c.w)};
      float4 d = *(const float4*)(pw + 8);
      float4 e = *(const float4*)(pw + 12);
      wihL[2 * g + 1][tid] = uint4{pkh(d.x, d.y), pkh(d.z, d.w), pkh(e.x, e.y), pkh(e.z, e.w)};
    }
    const float* po = Whh + (size_t)row * NH + half * 128 + cg * 16;
#pragma unroll
    for (int k = 0; k < 4; ++k) {
      float4 w4 = *(const float4*)(po + 4 * k);
      who_[g][2 * k] = pkh(w4.x, w4.y); who_[g][2 * k + 1] = pkh(w4.z, w4.w);
    }
    const float* pp = Whh + (size_t)row * NH + oh * 128 + cg * 16;
#pragma unroll
    for (int k = 0; k < 4; ++k) {
      float4 w4 = *(const float4*)(pp + 4 * k);
      whp_[g][2 * k] = pkh(w4.x, w4.y); whp_[g][2 * k + 1] = pkh(w4.z, w4.w);
    }
  }
  if (tid < 512) {
    const int g = tid >> 7, r = tid & 127;
    const int row = g * 256 + half * 128 + r;
    biasL[tid] = bih[row] + bhh[row];
  }
  if (tid < 128) hbuf[tid] = 0u;
  if (tid < 64) {
    float2 x2 = *(const float2*)(x + (size_t)b * NS * NV + 2 * tid);
    xbuf[tid] = pkh(x2.x, x2.y);
  }
  __syncthreads();

  float c = 0.0f;
#pragma unroll 1
  for (int t = 0; t < NS; ++t) {
    // wave1: prefetch x(t+1)
    float2 x2;
    if (tid >= 64 && tid < 128) {
      const int tn = (t + 1 < NS) ? t + 1 : t;
      x2 = *(const float2*)(x + ((size_t)b * NS + tn) * NV + 2 * (tid - 64));
    }
    // wave0: issue partner-h poll load (checked after phase A)
    u32 pv = 0;
    const u32* pslot = h0g + ((size_t)b * NS + (t > 0 ? t - 1 : 0)) * 128 + oh * 64;
    if (tid < 64 && t > 0) pv = gload(pslot + tid);

    float acc[4] = {0.f, 0.f, 0.f, 0.f};
    // phase A: Wih·x_t (weights from LDS) + Whh_own·h_own(t-1)
#pragma unroll
    for (int q = 0; q < 2; ++q) {
      uint4 xq = *(const uint4*)&xbuf[cg * 8 + 4 * q];
#pragma unroll
      for (int g = 0; g < 4; ++g) {
        uint4 w = wihL[2 * g + q][tid];
        acc[g] = fdot2(w.x, xq.x, acc[g]);
        acc[g] = fdot2(w.y, xq.y, acc[g]);
        acc[g] = fdot2(w.z, xq.z, acc[g]);
        acc[g] = fdot2(w.w, xq.w, acc[g]);
      }
    }
#pragma unroll
    for (int q = 0; q < 2; ++q) {
      uint4 hq = *(const uint4*)&hbuf[half * 64 + cg * 8 + 4 * q];
      u32 hw[4] = {hq.x, hq.y, hq.z, hq.w};
#pragma unroll
      for (int j = 0; j < 4; ++j)
#pragma unroll
        for (int g = 0; g < 4; ++g) acc[g] = fdot2(who_[g][4 * q + j], hw[j], acc[g]);
    }
    // wave0: complete poll, stage partner half
    if (tid < 64 && t > 0) {
      while (pv == SENT) { __builtin_amdgcn_s_sleep(8); pv = gload(pslot + tid); }
      hbuf[oh * 64 + tid] = pv;
    }
    __syncthreads();  // B1
    // phase B: Whh_partner·h_partner(t-1)
#pragma unroll
    for (int q = 0; q < 2; ++q) {
      uint4 hq = *(const uint4*)&hbuf[oh * 64 + cg * 8 + 4 * q];
      u32 hw[4] = {hq.x, hq.y, hq.z, hq.w};
#pragma unroll
      for (int j = 0; j < 4; ++j)
#pragma unroll
        for (int g = 0; g < 4; ++g) acc[g] = fdot2(whp_[g][4 * q + j], hw[j], acc[g]);
    }
#pragma unroll
    for (int g = 0; g < 4; ++g) {
      acc[g] += __shfl_xor(acc[g], 1);
      acc[g] += __shfl_xor(acc[g], 2);
      acc[g] += __shfl_xor(acc[g], 4);
    }
    if (cg == 0) {
      const float gi = sigm(acc[0] + biasL[rb2]);
      const float gf = sigm(acc[1] + biasL[128 + rb2]);
      const float gg = tanh_(acc[2] + biasL[256 + rb2]);
      const float go = sigm(acc[3] + biasL[384 + rb2]);
      c = gf * c + gi * gg;
      ((f16*)hbuf)[half * 128 + rb2] = (f16)(go * tanh_(c));
    }
    if (tid >= 64 && tid < 128 && t + 1 < NS) xbuf[tid - 64] = pkh(x2.x, x2.y);
    __syncthreads();  // B2
    // wave1: publish own h(t) half (atomic u32 stores -> agent-visible)
    if (tid >= 64 && tid < 128)
      gstore(h0g + ((size_t)b * NS + t) * 128 + half * 64 + (tid - 64),
             hbuf[half * 64 + (tid - 64)]);
  }
}

// ---------------------------------------------------------------------------
// scan1: layer-1 LSTM. Per-thread: Whh1 4x(16+16) cols in regs (64 u32);
// Wih1 4x32 cols = 32 reg u32 + 32 LDS u32 (128 KiB). With the (1024,4)
// bound the 96 register weights now fit the 128-VGPR budget.
// ---------------------------------------------------------------------------
__global__ __launch_bounds__(1024, 4) void scan1_kernel(
    const u32* __restrict__ h0g, const float* __restrict__ Wih,
    const float* __restrict__ Whh, const float* __restrict__ bih,
    const float* __restrict__ bhh, u32* __restrict__ outw) {
  const int blk = blockIdx.x;
  const int b = (blk & 7) | ((blk >> 4) << 3);
  const int half = (blk >> 3) & 1;
  const int oh = 1 - half;
  const int tid = threadIdx.x;
  const int cg = tid & 7;
  const int rb2 = tid >> 3;

  __shared__ uint4 wihL[8][1024];   // 128 KiB: quads 2,3 of each gate's Wih1 slice
  __shared__ u32 i0buf[128];        // h0(t) full (f16 pairs)
  __shared__ u32 hbuf[128];         // h1(t-1) full
  __shared__ float biasL[512];

  u32 wihR[4][8], who_[4][8], whp_[4][8];
#pragma unroll
  for (int g = 0; g < 4; ++g) {
    const int row = g * 256 + half * 128 + rb2;
    const float* pw = Wih + (size_t)row * NH + cg * 32;
#pragma unroll
    for (int k = 0; k < 4; ++k) {
      float4 w4 = *(const float4*)(pw + 4 * k);
      wihR[g][2 * k] = pkh(w4.x, w4.y); wihR[g][2 * k + 1] = pkh(w4.z, w4.w);
    }
    {
      float4 a = *(const float4*)(pw + 16);
      float4 c2 = *(const float4*)(pw + 20);
      wihL[2 * g][tid] = uint4{pkh(a.x, a.y), pkh(a.z, a.w), pkh(c2.x, c2.y), pkh(c2.z, c2.w)};
      float4 d = *(const float4*)(pw + 24);
      float4 e = *(const float4*)(pw + 28);
      wihL[2 * g + 1][tid] = uint4{pkh(d.x, d.y), pkh(d.z, d.w), pkh(e.x, e.y), pkh(e.z, e.w)};
    }
    const float* po = Whh + (size_t)row * NH + half * 128 + cg * 16;
#pragma unroll
    for (int k = 0; k < 4; ++k) {
      float4 w4 = *(const float4*)(po + 4 * k);
      who_[g][2 * k] = pkh(w4.x, w4.y); who_[g][2 * k + 1] = pkh(w4.z, w4.w);
    }
    const float* pp = Whh + (size_t)row * NH + oh * 128 + cg * 16;
#pragma unroll
    for (int k = 0; k < 4; ++k) {
      float4 w4 = *(const float4*)(pp + 4 * k);
      whp_[g][2 * k] = pkh(w4.x, w4.y); whp_[g][2 * k + 1] = pkh(w4.z, w4.w);
    }
  }
  if (tid < 512) {
    const int g = tid >> 7, r = tid & 127;
    const int row = g * 256 + half * 128 + r;
    biasL[tid] = bih[row] + bhh[row];
  }
  if (tid < 128) {
    hbuf[tid] = 0u;
    i0buf[tid] = h0g[(size_t)b * NS * 128 + tid];  // h0(0)
  }
  __syncthreads();

  float c = 0.0f;
#pragma unroll 1
  for (int t = 0; t < NS; ++t) {
    // wave1: prefetch h0(t+1)
    uint2 iv;
    if (tid >= 64 && tid < 128) {
      const int tn = (t + 1 < NS) ? t + 1 : t;
      iv = *(const uint2*)(h0g + ((size_t)b * NS + tn) * 128 + 2 * (tid - 64));
    }
    // wave0: issue partner-h1 poll
    u32 pv = 0;
    const u32* pslot = outw + ((size_t)b * NS + (t > 0 ? t - 1 : 0)) * 128 + oh * 64;
    if (tid < 64 && t > 0) pv = gload(pslot + tid);

    float acc[4] = {0.f, 0.f, 0.f, 0.f};
    // phase A: Wih1·h0(t) — quads 0,1 from regs; 2,3 weights from LDS
#pragma unroll
    for (int q = 0; q < 2; ++q) {
      uint4 iq = *(const uint4*)&i0buf[cg * 16 + 4 * q];
      u32 iw[4] = {iq.x, iq.y, iq.z, iq.w};
#pragma unroll
      for (int j = 0; j < 4; ++j)
#pragma unroll
        for (int g = 0; g < 4; ++g) acc[g] = fdot2(wihR[g][4 * q + j], iw[j], acc[g]);
    }
#pragma unroll
    for (int q = 0; q < 2; ++q) {
      uint4 iq = *(const uint4*)&i0buf[cg * 16 + 8 + 4 * q];
#pragma unroll
      for (int g = 0; g < 4; ++g) {
        uint4 w = wihL[2 * g + q][tid];
        acc[g] = fdot2(w.x, iq.x, acc[g]);
        acc[g] = fdot2(w.y, iq.y, acc[g]);
        acc[g] = fdot2(w.z, iq.z, acc[g]);
        acc[g] = fdot2(w.w, iq.w, acc[g]);
      }
    }
    // + Whh1_own·h1_own(t-1)
#pragma unroll
    for (int q = 0; q < 2; ++q) {
      uint4 hq = *(const uint4*)&hbuf[half * 64 + cg * 8 + 4 * q];
      u32 hw[4] = {hq.x, hq.y, hq.z, hq.w};
#pragma unroll
      for (int j = 0; j < 4; ++j)
#pragma unroll
        for (int g = 0; g < 4; ++g) acc[g] = fdot2(who_[g][4 * q + j], hw[j], acc[g]);
    }
    if (tid < 64 && t > 0) {
      while (pv == SENT) { __builtin_amdgcn_s_sleep(8); pv = gload(pslot + tid); }
      hbuf[oh * 64 + tid] = pv;
    }
    __syncthreads();  // B1
    // phase B: Whh1_partner·h1_partner(t-1)
#pragma unroll
    for (int q = 0; q < 2; ++q) {
      uint4 hq = *(const uint4*)&hbuf[oh * 64 + cg * 8 + 4 * q];
      u32 hw[4] = {hq.x, hq.y, hq.z, hq.w};
#pragma unroll
      for (int j = 0; j < 4; ++j)
#pragma unroll
        for (int g = 0; g < 4; ++g) acc[g] = fdot2(whp_[g][4 * q + j], hw[j], acc[g]);
    }
#pragma unroll
    for (int g = 0; g < 4; ++g) {
      acc[g] += __shfl_xor(acc[g], 1);
      acc[g] += __shfl_xor(acc[g], 2);
      acc[g] += __shfl_xor(acc[g], 4);
    }
    if (cg == 0) {
      const float gi = sigm(acc[0] + biasL[rb2]);
      const float gf = sigm(acc[1] + biasL[128 + rb2]);
      const float gg = tanh_(acc[2] + biasL[256 + rb2]);
      const float go = sigm(acc[3] + biasL[384 + rb2]);
      c = gf * c + gi * gg;
      ((f16*)hbuf)[half * 128 + rb2] = (f16)(go * tanh_(c));
    }
    if (tid >= 64 && tid < 128 && t + 1 < NS) {
      i0buf[2 * (tid - 64)] = iv.x;
      i0buf[2 * (tid - 64) + 1] = iv.y;
    }
    __syncthreads();  // B2
    // wave1: publish own h1(t) half into d_out slot
    if (tid >= 64 && tid < 128)
      gstore(outw + ((size_t)b * NS + t) * 128 + half * 64 + (tid - 64),
             hbuf[half * 64 + (tid - 64)]);
  }
}

// ---------------------------------------------------------------------------
// outproj: out = Wout·h1 + b, IN PLACE over d_out (h1 f16 slot bytes == out
// f32 row bytes). Unchanged from round 2 (was fast).
// ---------------------------------------------------------------------------
__global__ __launch_bounds__(1024) void outproj_kernel(
    const float* __restrict__ Wout, const float* __restrict__ bout,
    u32* __restrict__ io) {
  const int bs = blockIdx.x;           // 2048 blocks
  const int b = bs >> 4;
  const int t0 = (bs & 15) * 64;
  const int tid = threadIdx.x;
  const int p = tid & 7;
  const int vq = tid >> 3;

  __shared__ u32 h1L[64 * 128];
  __shared__ float outL[64 * 128];

  const u32* src = io + ((size_t)b * NS + t0) * 128;
  uint4 s0 = *(const uint4*)(src + (size_t)tid * 8);
  uint4 s1 = *(const uint4*)(src + (size_t)tid * 8 + 4);

  u32 wo[16];
  const float* pw = Wout + (size_t)vq * NH + p * 32;
#pragma unroll
  for (int k = 0; k < 8; ++k) {
    float4 w4 = *(const float4*)(pw + 4 * k);
    wo[2 * k] = pkh(w4.x, w4.y); wo[2 * k + 1] = pkh(w4.z, w4.w);
  }
  const float bo = bout[vq];

  *(uint4*)&h1L[tid * 8] = s0;
  *(uint4*)&h1L[tid * 8 + 4] = s1;
  __syncthreads();

#pragma unroll 4
  for (int s = 0; s < 64; ++s) {
    float oa = 0.0f;
#pragma unroll
    for (int q = 0; q < 4; ++q) {
      uint4 hq = *(const uint4*)&h1L[s * 128 + p * 16 + 4 * q];
      u32 hw[4] = {hq.x, hq.y, hq.z, hq.w};
#pragma unroll
      for (int j = 0; j < 4; ++j) oa = fdot2(wo[4 * q + j], hw[j], oa);
    }
    oa += __shfl_xor(oa, 1);
    oa += __shfl_xor(oa, 2);
    oa += __shfl_xor(oa, 4);
    if (p == 0) outL[s * 128 + vq] = oa + bo;
  }
  __syncthreads();

  float* df = (float*)(io + ((size_t)b * NS + t0) * 128);
  *(float4*)(df + (size_t)tid * 8) = *(float4*)&outL[tid * 8];
  *(float4*)(df + (size_t)tid * 8 + 4) = *(float4*)&outL[tid * 8 + 4];
}

extern "C" void kernel_launch(void* const* d_in, const int* in_sizes, int n_in,
                              void* d_out, int out_size, void* d_ws, size_t ws_size,
                              hipStream_t stream) {
  const float* x    = (const float*)d_in[0];
  const float* Wih0 = (const float*)d_in[1];
  const float* Whh0 = (const float*)d_in[2];
  const float* bih0 = (const float*)d_in[3];
  const float* bhh0 = (const float*)d_in[4];
  const float* Wih1 = (const float*)d_in[5];
  const float* Whh1 = (const float*)d_in[6];
  const float* bih1 = (const float*)d_in[7];
  const float* bhh1 = (const float*)d_in[8];
  const float* Wout = (const float*)d_in[9];
  const float* bout = (const float*)d_in[10];

  u32* h0g = (u32*)d_ws;   // [B][S][128 u32] = 64 MiB
  u32* hw1 = (u32*)d_out;  // h1 slots live inside d_out, overwritten in place

  const size_t slot_bytes = (size_t)NB * NS * 128 * 4;  // 64 MiB each
  hipMemsetAsync(d_ws, 0xFF, slot_bytes, stream);       // sentinel for scan0 exchange
  hipMemsetAsync(d_out, 0xFF, slot_bytes, stream);      // sentinel for scan1 exchange

  scan0_kernel<<<256, 1024, 0, stream>>>(x, Wih0, Whh0, bih0, bhh0, h0g);
  scan1_kernel<<<256, 1024, 0, stream>>>(h0g, Wih1, Whh1, bih1, bhh1, hw1);
  outproj_kernel<<<2048, 1024, 0, stream>>>(Wout, bout, hw1);
}

// Round 4
// 6848.552 us; speedup vs baseline: 11.0527x; 2.3534x over previous
//
#include <hip/hip_runtime.h>
#include <cstdint>

#define NB 128   // batch
#define NS 1024  // seq len
#define NV 128   // input dim
#define NH 256   // hidden
#define CH 128   // chunk length (timesteps per chunk)
#define NCH (NS / CH)

typedef _Float16 f16;
typedef _Float16 h2 __attribute__((ext_vector_type(2)));
typedef uint32_t u32;

static __device__ __forceinline__ float fdot2(u32 a, u32 b, float c) {
  return __builtin_amdgcn_fdot2(__builtin_bit_cast(h2, a),
                                __builtin_bit_cast(h2, b), c, false);
}
static __device__ __forceinline__ u32 pkh(float a, float b) {
  union { h2 h; u32 u; } cv; cv.h = h2{(f16)a, (f16)b}; return cv.u;
}
static __device__ __forceinline__ float sigm(float x) { return 1.f / (1.f + __expf(-x)); }
static __device__ __forceinline__ float tanh_(float x) { return 1.f - 2.f / (__expf(2.f * x) + 1.f); }

// ---------------------------------------------------------------------------
// gemm: xg(b,t,row) = W[row,:]·in(b,t,:) + bih[row] + bhh[row], stored f16.
// No sequential dependency -> fully parallel over (b,t).
// grid 256 = (b, t-half of chunk); 512 threads; thread owns rows tid, tid+512.
// Input vector is wave-uniform per t -> scalar loads; weights per-thread in
// VGPRs (gemm0: all 16 uint4/row; gemm1: 24 reg + 8 LDS per row).
// ---------------------------------------------------------------------------
template <int KU32, bool F32IN>
__global__ __launch_bounds__(512, 2) void gemm_kernel(
    const void* __restrict__ inp, const float* __restrict__ W,
    const float* __restrict__ bih, const float* __restrict__ bhh,
    f16* __restrict__ xg, int t0) {
  constexpr int NU4 = KU32 / 4;                 // uint4 per row (16 or 32)
  constexpr int NREG4 = (NU4 <= 16) ? NU4 : 24; // uint4 kept in registers
  constexpr int NLDS4 = NU4 - NREG4;            // uint4 spilled to LDS (0 or 8)

  __shared__ uint4 wL[NLDS4 > 0 ? NLDS4 : 1][1024];

  const int blk = blockIdx.x;
  const int b = blk >> 1;
  const int tpart = blk & 1;
  const int tid = threadIdx.x;
  const int r0 = tid, r1 = tid + 512;

  uint4 w0r[NREG4], w1r[NREG4];
  {
    const float* p0 = W + (size_t)r0 * (2 * KU32);
    const float* p1 = W + (size_t)r1 * (2 * KU32);
#pragma unroll
    for (int k = 0; k < NU4; ++k) {
      float4 a = *(const float4*)(p0 + 8 * k);
      float4 c = *(const float4*)(p0 + 8 * k + 4);
      uint4 v0 = uint4{pkh(a.x, a.y), pkh(a.z, a.w), pkh(c.x, c.y), pkh(c.z, c.w)};
      float4 d = *(const float4*)(p1 + 8 * k);
      float4 e = *(const float4*)(p1 + 8 * k + 4);
      uint4 v1 = uint4{pkh(d.x, d.y), pkh(d.z, d.w), pkh(e.x, e.y), pkh(e.z, e.w)};
      if constexpr (NLDS4 > 0) {
        if (k < NREG4) { w0r[k] = v0; w1r[k] = v1; }
        else { wL[k - NREG4][r0] = v0; wL[k - NREG4][r1] = v1; }
      } else {
        w0r[k] = v0; w1r[k] = v1;
      }
    }
  }
  const float bs0 = bih[r0] + bhh[r0];
  const float bs1 = bih[r1] + bhh[r1];
  __syncthreads();

#pragma unroll 1
  for (int tl = 0; tl < 64; ++tl) {
    const int tloc = tpart * 64 + tl;   // position within chunk
    const int t = t0 + tloc;            // absolute timestep
    float a0 = 0.f, a1 = 0.f;
#pragma unroll
    for (int k = 0; k < NU4; ++k) {
      u32 j0, j1, j2, j3;
      if constexpr (F32IN) {
        const float* ip = (const float*)inp + ((size_t)b * NS + t) * (2 * KU32);
        j0 = pkh(ip[8 * k + 0], ip[8 * k + 1]);
        j1 = pkh(ip[8 * k + 2], ip[8 * k + 3]);
        j2 = pkh(ip[8 * k + 4], ip[8 * k + 5]);
        j3 = pkh(ip[8 * k + 6], ip[8 * k + 7]);
      } else {
        const u32* ip = (const u32*)inp + ((size_t)b * NS + t) * KU32;
        j0 = ip[4 * k + 0]; j1 = ip[4 * k + 1];
        j2 = ip[4 * k + 2]; j3 = ip[4 * k + 3];
      }
      uint4 wa, wb;
      if constexpr (NLDS4 > 0) {
        wa = (k < NREG4) ? w0r[k] : wL[k - NREG4][r0];
        wb = (k < NREG4) ? w1r[k] : wL[k - NREG4][r1];
      } else {
        wa = w0r[k]; wb = w1r[k];
      }
      a0 = fdot2(wa.x, j0, a0); a0 = fdot2(wa.y, j1, a0);
      a0 = fdot2(wa.z, j2, a0); a0 = fdot2(wa.w, j3, a0);
      a1 = fdot2(wb.x, j0, a1); a1 = fdot2(wb.y, j1, a1);
      a1 = fdot2(wb.z, j2, a1); a1 = fdot2(wb.w, j3, a1);
    }
    f16* op = xg + ((size_t)b * CH + tloc) * 1024;
    op[r0] = (f16)(a0 + bs0);
    op[r1] = (f16)(a1 + bs1);
  }
}

// ---------------------------------------------------------------------------
// scan: self-contained LSTM recurrence, ONE WG per batch element (no cross-WG
// communication at all). 512 threads; thread owns gate rows r0=tid, r1=tid+512
// (tid<256: rows = i_u, g_u of unit u=tid; tid>=256: f_u, o_u of u=tid-256).
// Whh rows: 32 uint4 each, 24 in VGPRs + 8 in LDS. h(t-1): lane l holds h
// u32s {2l, 2l+1}; v_readlane broadcasts them as the SGPR operand of fdot2.
// xg (precomputed input contribution + biases) streamed from ws.
// ---------------------------------------------------------------------------
__global__ __launch_bounds__(512, 2) void scan_kernel(
    const f16* __restrict__ xg, const float* __restrict__ Whh,
    u32* __restrict__ slots, float* __restrict__ carry, int t0) {
  __shared__ uint4 wL[8][1024];     // 128 KiB: last 8 uint4 of each row
  __shared__ u32 hbuf[2][128];      // h(t-1), h(t) as 256 f16
  __shared__ float dbuf[2][256];    // f,o dots handed from hi-threads to lo

  const int b = blockIdx.x;
  const int tid = threadIdx.x;
  const int lane = tid & 63;
  const int u = tid & 255;
  const bool lo = tid < 256;
  const int r0 = tid, r1 = tid + 512;

  uint4 w0r[24], w1r[24];
  {
    const float* p0 = Whh + (size_t)r0 * NH;
    const float* p1 = Whh + (size_t)r1 * NH;
#pragma unroll
    for (int k = 0; k < 32; ++k) {
      float4 a = *(const float4*)(p0 + 8 * k);
      float4 c = *(const float4*)(p0 + 8 * k + 4);
      uint4 v0 = uint4{pkh(a.x, a.y), pkh(a.z, a.w), pkh(c.x, c.y), pkh(c.z, c.w)};
      float4 d = *(const float4*)(p1 + 8 * k);
      float4 e = *(const float4*)(p1 + 8 * k + 4);
      uint4 v1 = uint4{pkh(d.x, d.y), pkh(d.z, d.w), pkh(e.x, e.y), pkh(e.z, e.w)};
      if (k < 24) { w0r[k] = v0; w1r[k] = v1; }
      else { wL[k - 24][r0] = v0; wL[k - 24][r1] = v1; }
    }
  }
  float c = 0.f;
  if (t0 == 0) {
    if (tid < 128) { hbuf[0][tid] = 0u; }
  } else {
    if (lo) c = carry[b * 256 + u];
    if (tid < 128) hbuf[0][tid] = slots[((size_t)b * NS + t0 - 1) * 128 + tid];
  }
  __syncthreads();

#pragma unroll 1
  for (int tl = 0; tl < CH; ++tl) {
    const int cur = tl & 1, nxt = cur ^ 1;
    const int t = t0 + tl;

    // prefetch this step's xg early (consumed after the dots)
    const f16* xp = xg + ((size_t)b * CH + tl) * 1024;
    const float xa = (float)xp[r0];
    const float xb = (float)xp[r1];

    // lane-local copy of h(t-1): lane l holds u32s 2l, 2l+1
    const uint2 hv = *(const uint2*)&hbuf[cur][2 * lane];

    float a0 = 0.f, a1 = 0.f;
#pragma unroll
    for (int k = 0; k < 32; ++k) {
      const u32 hA = (u32)__builtin_amdgcn_readlane((int)hv.x, 2 * k);
      const u32 hB = (u32)__builtin_amdgcn_readlane((int)hv.y, 2 * k);
      const u32 hC = (u32)__builtin_amdgcn_readlane((int)hv.x, 2 * k + 1);
      const u32 hD = (u32)__builtin_amdgcn_readlane((int)hv.y, 2 * k + 1);
      const uint4 wa = (k < 24) ? w0r[k] : wL[k - 24][r0];
      const uint4 wb = (k < 24) ? w1r[k] : wL[k - 24][r1];
      a0 = fdot2(wa.x, hA, a0); a0 = fdot2(wa.y, hB, a0);
      a0 = fdot2(wa.z, hC, a0); a0 = fdot2(wa.w, hD, a0);
      a1 = fdot2(wb.x, hA, a1); a1 = fdot2(wb.y, hB, a1);
      a1 = fdot2(wb.z, hC, a1); a1 = fdot2(wb.w, hD, a1);
    }
    a0 += xa; a1 += xb;

    if (!lo) { dbuf[0][u] = a0; dbuf[1][u] = a1; }
    __syncthreads();  // B1: f,o dots visible to lo threads
    if (lo) {
      const float gi = sigm(a0);          // own: gate i of unit u
      const float gg = tanh_(a1);         // own: gate g of unit u
      const float gf = sigm(dbuf[0][u]);  // from thread 256+u
      const float go = sigm(dbuf[1][u]);
      c = gf * c + gi * gg;
      const float h = go * tanh_(c);
      ((f16*)hbuf[nxt])[u] = (f16)h;
      ((f16*)(slots + ((size_t)b * NS + t) * 128))[u] = (f16)h;
    }
    __syncthreads();  // B2: h(t) ready for next step
  }
  if (lo) carry[b * 256 + u] = c;
}

// ---------------------------------------------------------------------------
// outproj: out = Wout·h1 + b, IN PLACE over d_out slots (h1 f16 slot bytes ==
// out f32 row bytes). Unchanged from round 3 (validated).
// ---------------------------------------------------------------------------
__global__ __launch_bounds__(1024) void outproj_kernel(
    const float* __restrict__ Wout, const float* __restrict__ bout,
    u32* __restrict__ io) {
  const int bs = blockIdx.x;  // 2048 blocks
  const int b = bs >> 4;
  const int t0 = (bs & 15) * 64;
  const int tid = threadIdx.x;
  const int p = tid & 7;
  const int vq = tid >> 3;

  __shared__ u32 h1L[64 * 128];
  __shared__ float outL[64 * 128];

  const u32* src = io + ((size_t)b * NS + t0) * 128;
  uint4 s0 = *(const uint4*)(src + (size_t)tid * 8);
  uint4 s1 = *(const uint4*)(src + (size_t)tid * 8 + 4);

  u32 wo[16];
  const float* pw = Wout + (size_t)vq * NH + p * 32;
#pragma unroll
  for (int k = 0; k < 8; ++k) {
    float4 w4 = *(const float4*)(pw + 4 * k);
    wo[2 * k] = pkh(w4.x, w4.y); wo[2 * k + 1] = pkh(w4.z, w4.w);
  }
  const float bo = bout[vq];

  *(uint4*)&h1L[tid * 8] = s0;
  *(uint4*)&h1L[tid * 8 + 4] = s1;
  __syncthreads();

#pragma unroll 4
  for (int s = 0; s < 64; ++s) {
    float oa = 0.f;
#pragma unroll
    for (int q = 0; q < 4; ++q) {
      uint4 hq = *(const uint4*)&h1L[s * 128 + p * 16 + 4 * q];
      u32 hw[4] = {hq.x, hq.y, hq.z, hq.w};
#pragma unroll
      for (int j = 0; j < 4; ++j) oa = fdot2(wo[4 * q + j], hw[j], oa);
    }
    oa += __shfl_xor(oa, 1);
    oa += __shfl_xor(oa, 2);
    oa += __shfl_xor(oa, 4);
    if (p == 0) outL[s * 128 + vq] = oa + bo;
  }
  __syncthreads();

  float* df = (float*)(io + ((size_t)b * NS + t0) * 128);
  *(float4*)(df + (size_t)tid * 8) = *(float4*)&outL[tid * 8];
  *(float4*)(df + (size_t)tid * 8 + 4) = *(float4*)&outL[tid * 8 + 4];
}

extern "C" void kernel_launch(void* const* d_in, const int* in_sizes, int n_in,
                              void* d_out, int out_size, void* d_ws, size_t ws_size,
                              hipStream_t stream) {
  const float* x    = (const float*)d_in[0];
  const float* Wih0 = (const float*)d_in[1];
  const float* Whh0 = (const float*)d_in[2];
  const float* bih0 = (const float*)d_in[3];
  const float* bhh0 = (const float*)d_in[4];
  const float* Wih1 = (const float*)d_in[5];
  const float* Whh1 = (const float*)d_in[6];
  const float* bih1 = (const float*)d_in[7];
  const float* bhh1 = (const float*)d_in[8];
  const float* Wout = (const float*)d_in[9];
  const float* bout = (const float*)d_in[10];

  // ws: xg chunk buffer (f16 [B][CH][1024] = 32 MiB) + c-carry (128 KiB)
  f16* xgbuf = (f16*)d_ws;
  float* carry = (float*)((char*)d_ws + (size_t)NB * CH * 1024 * 2);
  // d_out slots: h0-seq -> (chunk-wise) h1-seq -> final f32 output, in place
  u32* slots = (u32*)d_out;

  for (int k = 0; k < NCH; ++k) {
    gemm_kernel<64, true><<<256, 512, 0, stream>>>(x, Wih0, bih0, bhh0, xgbuf, k * CH);
    scan_kernel<<<NB, 512, 0, stream>>>(xgbuf, Whh0, slots, carry, k * CH);
  }
  for (int k = 0; k < NCH; ++k) {
    gemm_kernel<128, false><<<256, 512, 0, stream>>>(slots, Wih1, bih1, bhh1, xgbuf, k * CH);
    scan_kernel<<<NB, 512, 0, stream>>>(xgbuf, Whh1, slots, carry, k * CH);
  }
  outproj_kernel<<<2048, 1024, 0, stream>>>(Wout, bout, slots);
}